// Round 1
// baseline (132.662 us; speedup 1.0000x reference)
//
#include <hip/hip_runtime.h>
#include <math.h>

#define B_ 64
#define E_ 256
#define S_ 32
#define H_ 16
#define HD_ 16
#define P_ 512
#define KC_ 46
#define DF_ 10
#define QKV_N (B_*S_*E_)   // 524288 floats per Q/K/V region

// ---------------- K1: pair selection, class ids, weights, multiplicities ----
__global__ __launch_bounds__(256) void k_setup(
    const int* __restrict__ labels0, const int* __restrict__ labels1,
    int* __restrict__ iidx_g, int* __restrict__ y_g,
    float* __restrict__ wy_g, float* __restrict__ c_g) {
  const int t = threadIdx.x;
  __shared__ int l0[B_], l1[B_];
  __shared__ int cnt[256];
  __shared__ int seli[P_], selj[P_];
  __shared__ float csh[B_], cls[KC_], wsh[KC_];
  if (t < B_) { l0[t] = labels0[t]; l1[t] = labels1[t]; csh[t] = 0.f; }
  if (t < KC_) cls[t] = 0.f;
  __syncthreads();
  // mask over 4096 flat (i,j); contiguous 16-chunk per thread preserves order
  unsigned bits = 0; int c = 0;
  for (int u = 0; u < 16; ++u) {
    int idx = t*16 + u; int i = idx >> 6, j = idx & 63;
    if (l1[i] == l1[j]) { bits |= 1u << u; ++c; }
  }
  cnt[t] = c; __syncthreads();
  for (int off = 1; off < 256; off <<= 1) {      // Hillis-Steele inclusive scan
    int v = (t >= off) ? cnt[t-off] : 0;
    __syncthreads();
    cnt[t] += v;
    __syncthreads();
  }
  const int total = cnt[255];
  int rank = cnt[t] - c;                          // exclusive prefix
  for (int p = t; p < P_; p += 256)               // fill_value=0 tail
    if (p >= total) { seli[p] = 0; selj[p] = 0; }
  for (int u = 0; u < 16; ++u) {
    if (bits & (1u << u)) {
      if (rank < P_) {
        int idx = t*16 + u;
        seli[rank] = idx >> 6; selj[rank] = idx & 63;
      }
      ++rank;
    }
  }
  __syncthreads();
  int myy[2]; float myv[2];
  for (int k = 0; k < 2; ++k) {
    int p = t + k*256;
    int i = seli[p], j = selj[p];
    atomicAdd(&csh[j], 1.0f);                     // key multiplicity (incl. pad)
    int la = l0[i], lb = l0[j];
    int yy;
    if (la == lb) yy = 0;
    else {
      int lo = la < lb ? la : lb, hi = la < lb ? lb : la;
      yy = 1 + lo*(DF_-1) - (lo*(lo-1))/2 + (hi - lo - 1);
    }
    float v = (p < total) ? 1.0f : 0.0f;
    atomicAdd(&cls[yy], v);
    myy[k] = yy; myv[k] = v;
    iidx_g[p] = i;
    y_g[p] = yy;
  }
  __syncthreads();
  if (t < KC_) wsh[t] = (cls[t] > 0.f) ? (1.0f/cls[t]) : 0.0f;
  __syncthreads();
  for (int k = 0; k < 2; ++k) {
    int p = t + k*256;
    wy_g[p] = wsh[myy[k]] * myv[k];
  }
  if (t < B_) c_g[t] = csh[t];
}

// ---------------- K2: per-batch QKV projection  X(32x256) @ W^T(256x768) ----
// grid (64 batches, 6 col-chunks of 128); LDS: xs 32KB + wt 16KB = 48KB
__global__ __launch_bounds__(256) void k_proj(
    const float* __restrict__ feat, const float* __restrict__ w,
    const float* __restrict__ bias, float* __restrict__ qkv) {
  const int b = blockIdx.x;
  const int cc = blockIdx.y;
  const int t = threadIdx.x;
  __shared__ float xs[E_*S_];        // xs[e'*32 + s] (same linear layout as feat[b])
  __shared__ float wt[32*128];       // wt[e't*128 + eo_l]
  const float* fb = feat + (size_t)b * (E_*S_);
#pragma unroll
  for (int it = 0; it < 8; ++it)
    ((float4*)xs)[it*256 + t] = ((const float4*)fb)[it*256 + t];
  const int eo_l = t & 31, sg = t >> 5;
  float acc[4][4];
#pragma unroll
  for (int k = 0; k < 4; ++k)
#pragma unroll
    for (int si = 0; si < 4; ++si) acc[k][si] = 0.f;
  const int row = t >> 1, f4base = (t & 1) * 4;
  for (int et = 0; et < 8; ++et) {
    const int etb = et * 32;
    __syncthreads();
#pragma unroll
    for (int u = 0; u < 4; ++u) {
      float4 v = ((const float4*)(w + (size_t)(cc*128 + row)*E_ + etb))[f4base + u];
      int ep = (f4base + u) * 4;
      wt[(ep+0)*128 + row] = v.x;
      wt[(ep+1)*128 + row] = v.y;
      wt[(ep+2)*128 + row] = v.z;
      wt[(ep+3)*128 + row] = v.w;
    }
    __syncthreads();
#pragma unroll
    for (int ee = 0; ee < 32; ++ee) {
      float xv[4], wv[4];
#pragma unroll
      for (int si = 0; si < 4; ++si) xv[si] = xs[(etb+ee)*32 + sg*4 + si];
#pragma unroll
      for (int k = 0; k < 4; ++k) wv[k] = wt[ee*128 + k*32 + eo_l];
#pragma unroll
      for (int k = 0; k < 4; ++k)
#pragma unroll
        for (int si = 0; si < 4; ++si)
          acc[k][si] = fmaf(wv[k], xv[si], acc[k][si]);
    }
  }
#pragma unroll
  for (int k = 0; k < 4; ++k) {
    int eo_g = cc*128 + k*32 + eo_l;
    float bv = bias[eo_g];
    int r = eo_g >> 8, e_in = eo_g & 255;
    float* dst = qkv + (size_t)r*QKV_N + (size_t)b*(S_*E_) + e_in;
#pragma unroll
    for (int si = 0; si < 4; ++si) {
      int s = sg*4 + si;
      dst[s*E_] = acc[k][si] + bv;
    }
  }
}

// ---------------- K3: weighted attention per (s,h): 64x64 score tile --------
__global__ __launch_bounds__(256) void k_attn(
    const float* __restrict__ qkv, const float* __restrict__ cmult,
    float* __restrict__ ob) {
  const int sh = blockIdx.x;
  const int s = sh >> 4, h = sh & 15;
  const int t = threadIdx.x;
  __shared__ float qs[64*17+16], ks[64*17+16], vs[64*17+16];  // +1 pad per row
  __shared__ float sc[64*65];                                  // +1 pad
  __shared__ float cm[64];
  const int a = t >> 2, dq = t & 3;
  {
    const size_t off = (size_t)a*(S_*E_) + (size_t)s*E_ + h*HD_ + dq*4;
    float4 q4 = *(const float4*)(qkv + off);
    float4 k4 = *(const float4*)(qkv + QKV_N + off);
    float4 v4 = *(const float4*)(qkv + 2*(size_t)QKV_N + off);
    int base = a*17 + dq*4;
    qs[base+0]=q4.x; qs[base+1]=q4.y; qs[base+2]=q4.z; qs[base+3]=q4.w;
    ks[base+0]=k4.x; ks[base+1]=k4.y; ks[base+2]=k4.z; ks[base+3]=k4.w;
    vs[base+0]=v4.x; vs[base+1]=v4.y; vs[base+2]=v4.z; vs[base+3]=v4.w;
  }
  if (t < 64) cm[t] = cmult[t];
  __syncthreads();
  float qv[16];
#pragma unroll
  for (int d = 0; d < 16; ++d) qv[d] = qs[a*17 + d];
  float scv[16];
  float mymax = -INFINITY;
#pragma unroll
  for (int i = 0; i < 16; ++i) {
    int b = dq*16 + i;
    float acc = 0.f;
#pragma unroll
    for (int d = 0; d < 16; ++d) acc = fmaf(qv[d], ks[b*17 + d], acc);
    acc *= 0.25f;                 // 1/sqrt(hd=16)
    scv[i] = acc;
    if (cm[b] > 0.f && acc > mymax) mymax = acc;
  }
  // row (a) spans 4 consecutive lanes -> shuffle reduce
  mymax = fmaxf(mymax, __shfl_xor(mymax, 1));
  mymax = fmaxf(mymax, __shfl_xor(mymax, 2));
  float z = 0.f;
#pragma unroll
  for (int i = 0; i < 16; ++i) {
    int b = dq*16 + i;
    float cb = cm[b];
    float e = (cb > 0.f) ? cb * __expf(scv[i] - mymax) : 0.f;
    sc[a*65 + b] = e;
    z += e;
  }
  z += __shfl_xor(z, 1);
  z += __shfl_xor(z, 2);
  __syncthreads();
  float out[4] = {0.f, 0.f, 0.f, 0.f};
#pragma unroll 8
  for (int b = 0; b < 64; ++b) {
    float e = sc[a*65 + b];
#pragma unroll
    for (int i = 0; i < 4; ++i)
      out[i] = fmaf(e, vs[b*17 + dq*4 + i], out[i]);
  }
  float rz = 1.0f / z;
  float* dst = ob + (size_t)a*(S_*E_) + (size_t)s*E_ + h*HD_ + dq*4;
#pragma unroll
  for (int i = 0; i < 4; ++i) dst[i] = out[i] * rz;
}

// ---------------- K4: out_proj ∘ final ∘ header ∘ logsumexp per batch row ---
// h[e] = sum_e' (sum_s Ob[a,s,e']*fw[s]) * Wout[e,e'] + bout[e]*sum(fw) + fb
__global__ __launch_bounds__(256) void k_epi(
    const float* __restrict__ ob, const float* __restrict__ wout,
    const float* __restrict__ bout, const float* __restrict__ fw,
    const float* __restrict__ fbi, const float* __restrict__ hw,
    const float* __restrict__ hb, float* __restrict__ logits,
    float* __restrict__ lse) {
  const int a = blockIdx.x, t = threadIdx.x;
  __shared__ float fws[S_], g[E_], hsh[E_], lg[KC_];
  if (t < S_) fws[t] = fw[t];
  __syncthreads();
  float acc = 0.f;
  const float* obp = ob + (size_t)a*(S_*E_) + t;
#pragma unroll
  for (int s = 0; s < S_; ++s) acc = fmaf(obp[s*E_], fws[s], acc);
  g[t] = acc;
  float sfw = 0.f;
#pragma unroll
  for (int s = 0; s < S_; ++s) sfw += fws[s];
  __syncthreads();
  float hv = 0.f;
  const float* wrow = wout + (size_t)t*E_;
#pragma unroll 8
  for (int e = 0; e < E_; ++e) hv = fmaf(g[e], wrow[e], hv);
  hv += bout[t]*sfw + fbi[0];
  hsh[t] = hv;
  __syncthreads();
  if (t < KC_) {
    float lv = 0.f;
    const float* hrow = hw + (size_t)t*E_;
#pragma unroll 8
    for (int e = 0; e < E_; ++e) lv = fmaf(hsh[e], hrow[e], lv);
    lv += hb[t];
    lg[t] = lv;
    logits[a*KC_ + t] = lv;
  }
  __syncthreads();
  if (t == 0) {
    float M = -INFINITY;
    for (int k = 0; k < KC_; ++k) M = fmaxf(M, lg[k]);
    float ssum = 0.f;
    for (int k = 0; k < KC_; ++k) ssum += __expf(lg[k] - M);
    lse[a] = M + __logf(ssum);
  }
}

// ---------------- K5: weighted cross-entropy reduction over 512 pairs -------
__global__ __launch_bounds__(256) void k_loss(
    const float* __restrict__ logits, const float* __restrict__ lse,
    const int* __restrict__ iidx, const int* __restrict__ yv,
    const float* __restrict__ wy, float* __restrict__ out) {
  const int t = threadIdx.x;
  float num = 0.f, den = 0.f;
  for (int p = t; p < P_; p += 256) {
    float w_ = wy[p];
    int a = iidx[p], yy = yv[p];
    num = fmaf(w_, lse[a] - logits[a*KC_ + yy], num);
    den += w_;
  }
#pragma unroll
  for (int o = 32; o > 0; o >>= 1) {
    num += __shfl_down(num, o);
    den += __shfl_down(den, o);
  }
  __shared__ float sn[4], sd[4];
  int wv_ = t >> 6;
  if ((t & 63) == 0) { sn[wv_] = num; sd[wv_] = den; }
  __syncthreads();
  if (t == 0) {
    float N = sn[0]+sn[1]+sn[2]+sn[3];
    float D = sd[0]+sd[1]+sd[2]+sd[3];
    out[0] = N / D;
  }
}

extern "C" void kernel_launch(void* const* d_in, const int* in_sizes, int n_in,
                              void* d_out, int out_size, void* d_ws, size_t ws_size,
                              hipStream_t stream) {
  const float* feat    = (const float*)d_in[0];
  const int*   labels0 = (const int*)d_in[1];
  const int*   labels1 = (const int*)d_in[2];
  const float* ipw     = (const float*)d_in[3];
  const float* ipb     = (const float*)d_in[4];
  const float* opw     = (const float*)d_in[5];
  const float* opb     = (const float*)d_in[6];
  const float* fw      = (const float*)d_in[7];
  const float* fbi     = (const float*)d_in[8];
  const float* hw      = (const float*)d_in[9];
  const float* hb      = (const float*)d_in[10];
  float* out = (float*)d_out;

  float* ws    = (float*)d_ws;
  int*   iidx  = (int*)d_ws;            // 512 ints
  int*   yv    = iidx + 512;            // 512 ints
  float* wy    = ws + 1024;             // 512 f
  float* cmult = ws + 1536;             // 64 f
  float* qkv   = ws + 2048;             // 3 * 524288 f
  float* ob    = qkv + 3*(size_t)QKV_N; // 524288 f
  float* logits= ob + QKV_N;            // 64*46 f
  float* lse   = logits + B_*KC_;       // 64 f   (total ~8.4 MB)

  k_setup<<<1, 256, 0, stream>>>(labels0, labels1, iidx, yv, wy, cmult);
  k_proj<<<dim3(B_, 6), 256, 0, stream>>>(feat, ipw, ipb, qkv);
  k_attn<<<S_*H_, 256, 0, stream>>>(qkv, cmult, ob);
  k_epi<<<B_, 256, 0, stream>>>(ob, opw, opb, fw, fbi, hw, hb, logits, lse);
  k_loss<<<1, 256, 0, stream>>>(logits, lse, iidx, yv, wy, out);
}